// Round 4
// baseline (274.726 us; speedup 1.0000x reference)
//
#include <hip/hip_runtime.h>

// ---------------------------------------------------------------- constants
static constexpr int Bn   = 8;
static constexpr int S    = 1024;
static constexpr int FT   = 16;
static constexpr int FDZ  = 768;
static constexpr int INK  = 784;   // FDZ + FT
static constexpr int KP   = 800;   // padded K for dense GEMM (25 * 32)
static constexpr int FDEC = 1024;
static constexpr int M    = Bn * S;   // 8192 rows
static constexpr int H    = 16;
static constexpr int FD   = 16;

typedef __bf16 bf16x8 __attribute__((ext_vector_type(8)));
typedef float  f32x4  __attribute__((ext_vector_type(4)));

__device__ __forceinline__ unsigned short f2b(float f) {
  return __builtin_bit_cast(unsigned short, static_cast<__bf16>(f));
}

__device__ __forceinline__ void gload16(const void* g, void* l) {
  __builtin_amdgcn_global_load_lds(
      (const __attribute__((address_space(1))) unsigned int*)g,
      (__attribute__((address_space(3))) unsigned int*)l, 16, 0, 0);
}

// ---------------------------------------------------------------- prep kernels
__global__ __launch_bounds__(256) void k_prep_xin(const float* __restrict__ z,
                                                  const float* __restrict__ rt,
                                                  unsigned short* __restrict__ xin) {
  int idx = blockIdx.x * 256 + threadIdx.x;
  if (idx >= M * KP) return;
  int m = idx / KP, c = idx - m * KP;
  float v = 0.f;
  if (c < FT)       v = rt[m * FT + c];
  else if (c < INK) v = z[(m >> 10) * FDZ + (c - FT)];
  xin[idx] = f2b(v);
}

__global__ __launch_bounds__(256) void k_cvt_pad(const float* __restrict__ src,
                                                 unsigned short* __restrict__ dst,
                                                 int R, int C, int Cp) {
  int idx = blockIdx.x * 256 + threadIdx.x;
  if (idx >= R * Cp) return;
  int r = idx / Cp, c = idx - r * Cp;
  dst[idx] = (c < C) ? f2b(src[(size_t)r * C + c]) : (unsigned short)0;
}

__global__ __launch_bounds__(256) void k_b3(const float* __restrict__ bq,
                                            const float* __restrict__ bk,
                                            const float* __restrict__ bv,
                                            float* __restrict__ b3) {
  int i = blockIdx.x * 256 + threadIdx.x;
  if (i < 1024)      b3[i] = bq[i];
  else if (i < 2048) b3[i] = bk[i - 1024];
  else if (i < 3072) b3[i] = bv[i - 2048];
}

// ---------------------------------------------------------------- GEMM (C = A @ B^T + bias)
// 256x128 tile, BK=32, 512 thr (8 waves, 4M x 2N, 64x64/wave).
// 4-slot LDS round-robin, staged 3 K-tiles ahead via global_load_lds;
// counted s_waitcnt vmcnt(6) (never 0 in main loop) + raw s_barrier.
// Read-side bank swizzle: granule g -> g ^ ((row>>1)&3), applied to the
// GLOBAL source when staging (LDS dest linear) and to ds_read addresses.
template<int EPI>
__global__ __launch_bounds__(512, 1) void k_gemm(const unsigned short* __restrict__ A, int lda,
                                                 const unsigned short* __restrict__ Bw, int ldb,
                                                 int K, int N, int nbx,
                                                 const float* __restrict__ bias,
                                                 float* __restrict__ Cf,
                                                 unsigned short* __restrict__ Cb) {
  __shared__ __align__(16) unsigned short As[4 * 256 * 32];   // 64 KiB
  __shared__ __align__(16) unsigned short Bs[4 * 128 * 32];   // 32 KiB
  const int tid = threadIdx.x, lane = tid & 63, w = tid >> 6;
  const int wr = w >> 1, wc = w & 1;
  const int lr = lane & 15, lg = lane >> 4;

  // bijective XCD remap (all grids have nwg % 8 == 0)
  const int nwg = gridDim.x;
  const int qx = nwg >> 3;
  const int swz = (blockIdx.x & 7) * qx + (blockIdx.x >> 3);
  const int m0 = (swz % nbx) * 256;
  const int n0 = (swz / nbx) * 128;

  const int nt = K >> 5;   // K-tiles of 32

  // ---- staging source pointers (per-lane, swizzled column granule) ----
  const int giA0 = w * 64 + lane;            // A granules 0..511
  const int rA0 = giA0 >> 2, cA0 = (giA0 & 3) ^ ((rA0 >> 1) & 3);
  const int giA1 = 512 + w * 64 + lane;      // A granules 512..1023
  const int rA1 = giA1 >> 2, cA1 = (giA1 & 3) ^ ((rA1 >> 1) & 3);
  const int giB0 = w * 64 + lane;            // B granules 0..511
  const int rB0 = giB0 >> 2, cB0 = (giB0 & 3) ^ ((rB0 >> 1) & 3);
  const unsigned short* srcA0 = A + (size_t)(m0 + rA0) * lda + cA0 * 8;
  const unsigned short* srcA1 = A + (size_t)(m0 + rA1) * lda + cA1 * 8;
  const unsigned short* srcB0 = Bw + (size_t)(n0 + rB0) * ldb + cB0 * 8;
  const int dA0 = (w * 64) * 8;              // wave-uniform LDS elem bases
  const int dA1 = (512 + w * 64) * 8;
  const int dB0 = (w * 64) * 8;

  // ---- fragment read offsets (swizzled) ----
  int offA[4], offB[4];
#pragma unroll
  for (int mi = 0; mi < 4; mi++) {
    int r = wr * 64 + mi * 16 + lr;
    offA[mi] = r * 32 + (lg ^ ((r >> 1) & 3)) * 8;
  }
#pragma unroll
  for (int ni = 0; ni < 4; ni++) {
    int r = wc * 64 + ni * 16 + lr;
    offB[ni] = r * 32 + (lg ^ ((r >> 1) & 3)) * 8;
  }

  f32x4 acc[4][4];
#pragma unroll
  for (int i = 0; i < 4; i++)
#pragma unroll
    for (int j = 0; j < 4; j++)
#pragma unroll
      for (int e = 0; e < 4; e++) acc[i][j][e] = 0.f;

  auto stage = [&](int tt) {
    const int sl = tt & 3;
    const size_t ko = (size_t)tt * 32;
    gload16(srcA0 + ko, &As[sl * 8192 + dA0]);
    gload16(srcA1 + ko, &As[sl * 8192 + dA1]);
    gload16(srcB0 + ko, &Bs[sl * 4096 + dB0]);
  };
  auto compute = [&](int tt) {
    const int sa = (tt & 3) * 8192;
    const int sb = (tt & 3) * 4096;
    bf16x8 af[4], bfr[4];
#pragma unroll
    for (int mi = 0; mi < 4; mi++)
      af[mi] = *reinterpret_cast<const bf16x8*>(&As[sa + offA[mi]]);
#pragma unroll
    for (int ni = 0; ni < 4; ni++)
      bfr[ni] = *reinterpret_cast<const bf16x8*>(&Bs[sb + offB[ni]]);
    __builtin_amdgcn_s_setprio(1);
#pragma unroll
    for (int mi = 0; mi < 4; mi++)
#pragma unroll
      for (int ni = 0; ni < 4; ni++)
        acc[mi][ni] = __builtin_amdgcn_mfma_f32_16x16x32_bf16(af[mi], bfr[ni], acc[mi][ni], 0, 0, 0);
    __builtin_amdgcn_s_setprio(0);
  };

  // prologue: 3 K-tiles in flight
  stage(0); stage(1); stage(2);

  int t = 0;
  for (; t < nt - 3; ++t) {
    asm volatile("s_waitcnt vmcnt(6)" ::: "memory");   // tile t landed; 2 in flight
    __builtin_amdgcn_s_barrier();
    stage(t + 3);
    compute(t);
  }
  asm volatile("s_waitcnt vmcnt(6)" ::: "memory");
  __builtin_amdgcn_s_barrier();
  compute(t); ++t;
  asm volatile("s_waitcnt vmcnt(3)" ::: "memory");
  __builtin_amdgcn_s_barrier();
  compute(t); ++t;
  asm volatile("s_waitcnt vmcnt(0)" ::: "memory");
  __builtin_amdgcn_s_barrier();
  compute(t);

  // epilogue
#pragma unroll
  for (int mi = 0; mi < 4; mi++)
#pragma unroll
    for (int ni = 0; ni < 4; ni++) {
      int col = n0 + wc * 64 + ni * 16 + lr;
      float bv = bias ? bias[col] : 0.f;
#pragma unroll
      for (int j = 0; j < 4; j++) {
        int row = m0 + wr * 64 + mi * 16 + lg * 4 + j;
        float v = acc[mi][ni][j] + bv;
        if constexpr (EPI == 0) {
          Cf[(size_t)row * N + col] = v;
        } else if constexpr (EPI == 1) {
          Cb[(size_t)row * N + col] = f2b(v);
        } else {
          size_t o = (size_t)row * N + col;
          float xv = Cf[o] + v;
          Cf[o] = xv;
          Cb[o] = f2b(xv);
        }
      }
    }
}

// ---------------------------------------------------------------- LayerNorm (per row of 1024)
__global__ __launch_bounds__(256) void k_ln(const float* __restrict__ x,
                                            const float* __restrict__ g,
                                            const float* __restrict__ bta,
                                            unsigned short* __restrict__ xn) {
  int row = blockIdx.x;
  int tid = threadIdx.x;
  const float4 v = *reinterpret_cast<const float4*>(&x[(size_t)row * 1024 + tid * 4]);
  float s = v.x + v.y + v.z + v.w;
  float q = v.x * v.x + v.y * v.y + v.z * v.z + v.w * v.w;
  for (int off = 32; off; off >>= 1) { s += __shfl_down(s, off); q += __shfl_down(q, off); }
  __shared__ float ss[4], qq[4];
  int wid = tid >> 6, lane = tid & 63;
  if (lane == 0) { ss[wid] = s; qq[wid] = q; }
  __syncthreads();
  float St = ss[0] + ss[1] + ss[2] + ss[3];
  float Qt = qq[0] + qq[1] + qq[2] + qq[3];
  float mu  = St * (1.f / 1024.f);
  float var = Qt * (1.f / 1024.f) - mu * mu;
  float rstd = rsqrtf(var + 1e-6f);
  int c = tid * 4;
  unsigned short o[4];
  o[0] = f2b(g[c + 0] * (v.x - mu) * rstd + bta[c + 0]);
  o[1] = f2b(g[c + 1] * (v.y - mu) * rstd + bta[c + 1]);
  o[2] = f2b(g[c + 2] * (v.z - mu) * rstd + bta[c + 2]);
  o[3] = f2b(g[c + 3] * (v.w - mu) * rstd + bta[c + 3]);
  *reinterpret_cast<uint2*>(&xn[(size_t)row * 1024 + c]) = *reinterpret_cast<uint2*>(o);
}

// ---------------------------------------------------------------- flash attention
// grid (128 bh, 4 pairs); 512 thr = 8 waves x 16 q-rows. Block does q-tiles {y, 7-y}
// (balanced 18 k-tiles). Swapped QK^T: lane holds 16 scores of ONE q-row ->
// in-register softmax + 2 shuffles. Async reg-prefetch of next K/V tile.
__global__ __launch_bounds__(512, 4) void k_attn(const unsigned short* __restrict__ qkv,
                                                 unsigned short* __restrict__ o) {
  __shared__ unsigned short Ks[64][72];
  __shared__ unsigned short Vt[64][72];      // Vt[d][swz(k)], swz: k-blk ^= (d>>3)
  __shared__ unsigned short Pl[8][16][72];
  const int tid = threadIdx.x, lane = tid & 63, w = tid >> 6;
  const int bh = blockIdx.x, b = bh >> 4, h = bh & 15;
  const int lr = lane & 15, lg = lane >> 4, lg4 = lg * 4;
  const int krow = tid >> 3, c8 = (tid & 7) << 3;
  const int kb8 = krow >> 3, kl = krow & 7, vq = tid & 7;
  const float slope2 = exp2f(-0.5f * (float)(h + 1)) * 1.44269504f;
  const float sc2 = 0.125f * 1.44269504f;

  for (int ph = 0; ph < 2; ++ph) {
    const int qb = ph ? (7 - (int)blockIdx.y) : (int)blockIdx.y;
    const int q0 = qb * 128;
    const int qlo = q0 + w * 16;
    const int qa = qlo + lr;                 // this lane's q-row (for scores)

    bf16x8 qf[2];
    {
      const unsigned short* qp = &qkv[(size_t)(b * 1024 + qlo + lr) * 3072 + h * 64];
      qf[0] = *reinterpret_cast<const bf16x8*>(qp + lg * 8);
      qf[1] = *reinterpret_cast<const bf16x8*>(qp + 32 + lg * 8);
    }
    float mrun = -3.0e38f, lrun = 0.f;
    f32x4 accO[4];
    for (int dn = 0; dn < 4; dn++)
      for (int e = 0; e < 4; e++) accO[dn][e] = 0.f;

    const int nt = 2 * qb + 2;
    uint4 kr, vr;
    {
      const size_t base = (size_t)(b * 1024 + krow) * 3072 + h * 64;
      kr = *reinterpret_cast<const uint4*>(&qkv[base + 1024 + c8]);
      vr = *reinterpret_cast<const uint4*>(&qkv[base + 2048 + c8]);
    }
    for (int kt = 0; kt < nt; ++kt) {
      const int kb = kt << 6;
      __syncthreads();                        // prior tile's readers done
      *reinterpret_cast<uint4*>(&Ks[krow][c8]) = kr;
      {
        const unsigned short* vs = reinterpret_cast<const unsigned short*>(&vr);
        for (int j = 0; j < 8; j++)
          Vt[c8 + j][((kb8 ^ vq) << 3) | kl] = vs[j];
      }
      __syncthreads();                        // LDS ready
      if (kt + 1 < nt) {                      // prefetch next tile under compute
        const size_t base = (size_t)(b * 1024 + kb + 64 + krow) * 3072 + h * 64;
        kr = *reinterpret_cast<const uint4*>(&qkv[base + 1024 + c8]);
        vr = *reinterpret_cast<const uint4*>(&qkv[base + 2048 + c8]);
      }
      if (kb <= qlo + 15) {                   // wave-uniform skip of fully-masked tile
        f32x4 sf[4];
        for (int kn = 0; kn < 4; kn++) {
          f32x4 zz;
          for (int e = 0; e < 4; e++) zz[e] = 0.f;
          bf16x8 kf0 = *reinterpret_cast<const bf16x8*>(&Ks[kn * 16 + lr][lg * 8]);
          bf16x8 kf1 = *reinterpret_cast<const bf16x8*>(&Ks[kn * 16 + lr][32 + lg * 8]);
          zz = __builtin_amdgcn_mfma_f32_16x16x32_bf16(kf0, qf[0], zz, 0, 0, 0);
          zz = __builtin_amdgcn_mfma_f32_16x16x32_bf16(kf1, qf[1], zz, 0, 0, 0);
          sf[kn] = zz;                        // sf[kn][j]: k=kb+kn*16+lg4+j, q=qa
        }
        const bool needmask = (kb + 63 > qlo);
        float sc[4][4];
        float ml = -3.0e38f;
        for (int kn = 0; kn < 4; kn++) {
          float alib = slope2 * (float)(kb + kn * 16 + lg4);
          for (int j = 0; j < 4; j++) {
            float v = fmaf(sf[kn][j], sc2, alib + slope2 * (float)j);
            if (needmask && (kb + kn * 16 + lg4 + j > qa)) v = -3.0e38f;
            sc[kn][j] = v;
            ml = fmaxf(ml, v);
          }
        }
        ml = fmaxf(ml, __shfl_xor(ml, 16));
        ml = fmaxf(ml, __shfl_xor(ml, 32));
        float mnew = fmaxf(mrun, ml);
        float f = exp2f(mrun - mnew);
        float rs = 0.f;
        for (int kn = 0; kn < 4; kn++) {
          __bf16 pb[4];
          for (int j = 0; j < 4; j++) {
            float pv = exp2f(sc[kn][j] - mnew);
            rs += pv;
            pb[j] = (__bf16)pv;
          }
          *reinterpret_cast<uint2*>(&Pl[w][lr][kn * 16 + lg4]) =
              *reinterpret_cast<uint2*>(pb);
        }
        rs += __shfl_xor(rs, 16);
        rs += __shfl_xor(rs, 32);
        lrun = lrun * f + rs;
        mrun = mnew;
        float fj[4];
        for (int j = 0; j < 4; j++) fj[j] = __shfl(f, (lane & 48) | (lg4 + j));
        for (int dn = 0; dn < 4; dn++)
          for (int j = 0; j < 4; j++) accO[dn][j] *= fj[j];
        asm volatile("s_waitcnt lgkmcnt(0)" ::: "memory");   // own P writes drained
        for (int ks = 0; ks < 2; ks++) {
          bf16x8 pa = *reinterpret_cast<const bf16x8*>(&Pl[w][lr][ks * 32 + lg * 8]);
          for (int dn = 0; dn < 4; dn++) {
            int d = dn * 16 + lr;
            bf16x8 vb = *reinterpret_cast<const bf16x8*>(
                &Vt[d][(((ks * 4 + lg) ^ (d >> 3)) << 3)]);
            accO[dn] = __builtin_amdgcn_mfma_f32_16x16x32_bf16(pa, vb, accO[dn], 0, 0, 0);
          }
        }
      }
    }
    float linv[4];
    for (int j = 0; j < 4; j++)
      linv[j] = 1.f / __shfl(lrun, (lane & 48) | (lg4 + j));
    for (int dn = 0; dn < 4; dn++)
      for (int j = 0; j < 4; j++) {
        int row = qlo + lg4 + j;
        int d = dn * 16 + lr;
        o[(size_t)(b * 1024 + row) * 1024 + h * 64 + d] = f2b(accO[dn][j] * linv[j]);
      }
  }
}

// ---------------------------------------------------------------- decode GEMM (N=16) + transpose
__global__ __launch_bounds__(256) void k_dec(const unsigned short* __restrict__ xb,
                                             const unsigned short* __restrict__ dw,
                                             const float* __restrict__ db,
                                             float* __restrict__ out) {
  const int tid = threadIdx.x, lane = tid & 63, w = tid >> 6;
  const int lr = lane & 15, lg = lane >> 4;
  const int sb = blockIdx.x * 4 + w;
  const int r0 = sb * 16;
  f32x4 acc;
  for (int e = 0; e < 4; e++) acc[e] = 0.f;
  const unsigned short* arow = &xb[(size_t)(r0 + lr) * 1024];
  const unsigned short* brow = &dw[(size_t)lr * 1024];
  for (int k0 = 0; k0 < 1024; k0 += 32) {
    bf16x8 af = *reinterpret_cast<const bf16x8*>(arow + k0 + lg * 8);
    bf16x8 bf = *reinterpret_cast<const bf16x8*>(brow + k0 + lg * 8);
    acc = __builtin_amdgcn_mfma_f32_16x16x32_bf16(af, bf, acc, 0, 0, 0);
  }
  const int b = r0 >> 10;
  const int sl = (r0 & 1023) + lg * 4;
  float bias = db[lr];
  float4 res;
  res.x = acc[0] + bias; res.y = acc[1] + bias; res.z = acc[2] + bias; res.w = acc[3] + bias;
  *reinterpret_cast<float4*>(&out[(size_t)(b * 16 + lr) * 1024 + sl]) = res;
}

// ---------------------------------------------------------------- launcher
extern "C" void kernel_launch(void* const* d_in, const int* in_sizes, int n_in,
                              void* d_out, int out_size, void* d_ws, size_t ws_size,
                              hipStream_t stream) {
  (void)in_sizes; (void)n_in; (void)out_size;
  const float* z   = (const float*)d_in[0];
  const float* rt  = (const float*)d_in[1];
  const float* dnw = (const float*)d_in[2];
  const float* dnb = (const float*)d_in[3];
  const float* lng = (const float*)d_in[4];
  const float* lnb = (const float*)d_in[5];
  const float* wq  = (const float*)d_in[6];
  const float* bq  = (const float*)d_in[7];
  const float* wk  = (const float*)d_in[8];
  const float* bk  = (const float*)d_in[9];
  const float* wv  = (const float*)d_in[10];
  const float* bv  = (const float*)d_in[11];
  const float* wo  = (const float*)d_in[12];
  const float* bo  = (const float*)d_in[13];
  const float* dcw = (const float*)d_in[14];
  const float* dcb = (const float*)d_in[15];
  float* out = (float*)d_out;

  char* p = (char*)d_ws;
  float* x            = (float*)p;          p += (size_t)M * FDEC * 4;
  unsigned short* xin = (unsigned short*)p; p += (size_t)M * KP * 2;
  unsigned short* wdn = (unsigned short*)p; p += (size_t)FDEC * KP * 2;
  unsigned short* xn  = (unsigned short*)p; p += (size_t)M * FDEC * 2;
  unsigned short* w3  = (unsigned short*)p; p += (size_t)3 * FDEC * FDEC * 2;
  float* b3           = (float*)p;          p += (size_t)3 * FDEC * 4;
  unsigned short* qkv = (unsigned short*)p; p += (size_t)M * 3 * FDEC * 2;
  unsigned short* ob  = (unsigned short*)p; p += (size_t)M * FDEC * 2;
  unsigned short* wob = (unsigned short*)p; p += (size_t)FDEC * FDEC * 2;
  unsigned short* dwb = (unsigned short*)p; p += (size_t)FD * FDEC * 2;
  if ((size_t)(p - (char*)d_ws) > ws_size) return;

  k_prep_xin<<<(M * KP) / 256, 256, 0, stream>>>(z, rt, xin);
  k_cvt_pad<<<(FDEC * KP) / 256, 256, 0, stream>>>(dnw, wdn, FDEC, INK, KP);
  k_cvt_pad<<<(FDEC * FDEC) / 256, 256, 0, stream>>>(wq, w3, FDEC, FDEC, FDEC);
  k_cvt_pad<<<(FDEC * FDEC) / 256, 256, 0, stream>>>(wk, w3 + FDEC * FDEC, FDEC, FDEC, FDEC);
  k_cvt_pad<<<(FDEC * FDEC) / 256, 256, 0, stream>>>(wv, w3 + 2 * FDEC * FDEC, FDEC, FDEC, FDEC);
  k_cvt_pad<<<(FDEC * FDEC) / 256, 256, 0, stream>>>(wo, wob, FDEC, FDEC, FDEC);
  k_cvt_pad<<<(FD * FDEC) / 256, 256, 0, stream>>>(dcw, dwb, FD, FDEC, FDEC);
  k_b3<<<12, 256, 0, stream>>>(bq, bk, bv, b3);

  // grids: (M/256) x (N/128), flattened 1D (all % 8 == 0)
  k_gemm<0><<<(M / 256) * (FDEC / 128), 512, 0, stream>>>(xin, KP, wdn, KP, KP, FDEC, M / 256, dnb, x, nullptr);
  k_ln<<<M, 256, 0, stream>>>(x, lng, lnb, xn);
  k_gemm<1><<<(M / 256) * (3 * FDEC / 128), 512, 0, stream>>>(xn, FDEC, w3, FDEC, FDEC, 3 * FDEC, M / 256, b3, nullptr, qkv);
  k_attn<<<dim3(Bn * H, 4), 512, 0, stream>>>(qkv, ob);
  k_gemm<2><<<(M / 256) * (FDEC / 128), 512, 0, stream>>>(ob, FDEC, wob, FDEC, FDEC, FDEC, M / 256, bo, x, xn);
  k_dec<<<M / 64, 256, 0, stream>>>(xn, dwb, dcb, out);
}

// Round 5
// 243.507 us; speedup vs baseline: 1.1282x; 1.1282x over previous
//
#include <hip/hip_runtime.h>

// ---------------------------------------------------------------- constants
static constexpr int Bn   = 8;
static constexpr int S    = 1024;
static constexpr int FT   = 16;
static constexpr int FDZ  = 768;
static constexpr int INK  = 784;   // FDZ + FT
static constexpr int KP   = 800;   // padded K for dense GEMM (25 * 32)
static constexpr int FDEC = 1024;
static constexpr int M    = Bn * S;   // 8192 rows
static constexpr int H    = 16;
static constexpr int FD   = 16;

typedef __bf16 bf16x8 __attribute__((ext_vector_type(8)));
typedef float  f32x4  __attribute__((ext_vector_type(4)));

__device__ __forceinline__ unsigned short f2b(float f) {
  return __builtin_bit_cast(unsigned short, static_cast<__bf16>(f));
}

__device__ __forceinline__ void gload16(const void* g, void* l) {
  __builtin_amdgcn_global_load_lds(
      (const __attribute__((address_space(1))) unsigned int*)g,
      (__attribute__((address_space(3))) unsigned int*)l, 16, 0, 0);
}

// ---------------------------------------------------------------- prep kernels
__global__ __launch_bounds__(256) void k_prep_xin(const float* __restrict__ z,
                                                  const float* __restrict__ rt,
                                                  unsigned short* __restrict__ xin) {
  int idx = blockIdx.x * 256 + threadIdx.x;
  if (idx >= M * KP) return;
  int m = idx / KP, c = idx - m * KP;
  float v = 0.f;
  if (c < FT)       v = rt[m * FT + c];
  else if (c < INK) v = z[(m >> 10) * FDZ + (c - FT)];
  xin[idx] = f2b(v);
}

__global__ __launch_bounds__(256) void k_cvt_pad(const float* __restrict__ src,
                                                 unsigned short* __restrict__ dst,
                                                 int R, int C, int Cp) {
  int idx = blockIdx.x * 256 + threadIdx.x;
  if (idx >= R * Cp) return;
  int r = idx / Cp, c = idx - r * Cp;
  dst[idx] = (c < C) ? f2b(src[(size_t)r * C + c]) : (unsigned short)0;
}

__global__ __launch_bounds__(256) void k_b3(const float* __restrict__ bq,
                                            const float* __restrict__ bk,
                                            const float* __restrict__ bv,
                                            float* __restrict__ b3) {
  int i = blockIdx.x * 256 + threadIdx.x;
  if (i < 1024)      b3[i] = bq[i];
  else if (i < 2048) b3[i] = bk[i - 1024];
  else if (i < 3072) b3[i] = bv[i - 2048];
}

// ---------------------------------------------------------------- GEMM (C = A @ B^T + bias)
// 256x128 tile, BK=32, 512 thr (8 waves, 4M x 2N, 64x64/wave).
// 3-slot LDS round-robin, depth-2 prefetch via global_load_lds;
// counted s_waitcnt vmcnt(3) (never 0 in main loop) + raw s_barrier.
// 72 KiB LDS -> 2 blocks/CU. XCD map: XCD k owns m-tiles [4k,4k+4) x all n
// (A-chunk 2 MB -> L2-resident per XCD). Bank swizzle: granule ^= (row>>1)&3,
// applied to GLOBAL source (LDS dest linear, rule #21) and to ds_read addrs.
template<int EPI>
__global__ __launch_bounds__(512, 4) void k_gemm(const unsigned short* __restrict__ A, int lda,
                                                 const unsigned short* __restrict__ Bw, int ldb,
                                                 int K, int N,
                                                 const float* __restrict__ bias,
                                                 float* __restrict__ Cf,
                                                 unsigned short* __restrict__ Cb) {
  __shared__ __align__(16) unsigned short As[3 * 256 * 32];   // 48 KiB
  __shared__ __align__(16) unsigned short Bs[3 * 128 * 32];   // 24 KiB
  const int tid = threadIdx.x, lane = tid & 63, w = tid >> 6;
  const int wr = w >> 1, wc = w & 1;
  const int lr = lane & 15, lg = lane >> 4;

  // XCD-locality map: xcd = bid&7 owns m-tiles [4*xcd, 4*xcd+4), n-major chunk
  const int xcd = blockIdx.x & 7;
  const int j   = blockIdx.x >> 3;
  const int m0  = (xcd * 4 + (j & 3)) * 256;
  const int n0  = (j >> 2) * 128;

  const int nt = K >> 5;   // K-tiles of 32

  // ---- staging source pointers (per-lane, swizzled column granule) ----
  const int giA0 = w * 64 + lane;            // A granules 0..511
  const int rA0 = giA0 >> 2, cA0 = (giA0 & 3) ^ ((rA0 >> 1) & 3);
  const int giA1 = 512 + w * 64 + lane;      // A granules 512..1023
  const int rA1 = giA1 >> 2, cA1 = (giA1 & 3) ^ ((rA1 >> 1) & 3);
  const int giB0 = w * 64 + lane;            // B granules 0..511
  const int rB0 = giB0 >> 2, cB0 = (giB0 & 3) ^ ((rB0 >> 1) & 3);
  const unsigned short* srcA0 = A + (size_t)(m0 + rA0) * lda + cA0 * 8;
  const unsigned short* srcA1 = A + (size_t)(m0 + rA1) * lda + cA1 * 8;
  const unsigned short* srcB0 = Bw + (size_t)(n0 + rB0) * ldb + cB0 * 8;
  const int dA0 = (w * 64) * 8;              // wave-uniform LDS elem bases
  const int dA1 = (512 + w * 64) * 8;
  const int dB0 = (w * 64) * 8;

  // ---- fragment read offsets (swizzled) ----
  int offA[4], offB[4];
#pragma unroll
  for (int mi = 0; mi < 4; mi++) {
    int r = wr * 64 + mi * 16 + lr;
    offA[mi] = r * 32 + (lg ^ ((r >> 1) & 3)) * 8;
  }
#pragma unroll
  for (int ni = 0; ni < 4; ni++) {
    int r = wc * 64 + ni * 16 + lr;
    offB[ni] = r * 32 + (lg ^ ((r >> 1) & 3)) * 8;
  }

  f32x4 acc[4][4];
#pragma unroll
  for (int i = 0; i < 4; i++)
#pragma unroll
    for (int j2 = 0; j2 < 4; j2++)
#pragma unroll
      for (int e = 0; e < 4; e++) acc[i][j2][e] = 0.f;

  auto stage = [&](int tt) {
    const int sl = tt % 3;
    const size_t ko = (size_t)tt * 32;
    gload16(srcA0 + ko, &As[sl * 8192 + dA0]);
    gload16(srcA1 + ko, &As[sl * 8192 + dA1]);
    gload16(srcB0 + ko, &Bs[sl * 4096 + dB0]);
  };
  auto compute = [&](int tt) {
    const int sa = (tt % 3) * 8192;
    const int sb = (tt % 3) * 4096;
    bf16x8 af[4], bfr[4];
#pragma unroll
    for (int mi = 0; mi < 4; mi++)
      af[mi] = *reinterpret_cast<const bf16x8*>(&As[sa + offA[mi]]);
#pragma unroll
    for (int ni = 0; ni < 4; ni++)
      bfr[ni] = *reinterpret_cast<const bf16x8*>(&Bs[sb + offB[ni]]);
    __builtin_amdgcn_s_setprio(1);
#pragma unroll
    for (int mi = 0; mi < 4; mi++)
#pragma unroll
      for (int ni = 0; ni < 4; ni++)
        acc[mi][ni] = __builtin_amdgcn_mfma_f32_16x16x32_bf16(af[mi], bfr[ni], acc[mi][ni], 0, 0, 0);
    __builtin_amdgcn_s_setprio(0);
  };

  // prologue: 2 K-tiles in flight
  stage(0); stage(1);

  int t = 0;
  for (; t < nt - 2; ++t) {
    asm volatile("s_waitcnt vmcnt(3)" ::: "memory");   // tile t landed; t+1 in flight
    __builtin_amdgcn_s_barrier();
    stage(t + 2);
    compute(t);
  }
  asm volatile("s_waitcnt vmcnt(3)" ::: "memory");
  __builtin_amdgcn_s_barrier();
  compute(t); ++t;
  asm volatile("s_waitcnt vmcnt(0)" ::: "memory");
  __builtin_amdgcn_s_barrier();
  compute(t);

  // epilogue
#pragma unroll
  for (int mi = 0; mi < 4; mi++)
#pragma unroll
    for (int ni = 0; ni < 4; ni++) {
      int col = n0 + wc * 64 + ni * 16 + lr;
      float bv = bias ? bias[col] : 0.f;
#pragma unroll
      for (int jj = 0; jj < 4; jj++) {
        int row = m0 + wr * 64 + mi * 16 + lg * 4 + jj;
        float v = acc[mi][ni][jj] + bv;
        if constexpr (EPI == 0) {
          Cf[(size_t)row * N + col] = v;
        } else if constexpr (EPI == 1) {
          Cb[(size_t)row * N + col] = f2b(v);
        } else {
          size_t o = (size_t)row * N + col;
          float xv = Cf[o] + v;
          Cf[o] = xv;
          Cb[o] = f2b(xv);
        }
      }
    }
}

// ---------------------------------------------------------------- LayerNorm (per row of 1024)
__global__ __launch_bounds__(256) void k_ln(const float* __restrict__ x,
                                            const float* __restrict__ g,
                                            const float* __restrict__ bta,
                                            unsigned short* __restrict__ xn) {
  int row = blockIdx.x;
  int tid = threadIdx.x;
  const float4 v = *reinterpret_cast<const float4*>(&x[(size_t)row * 1024 + tid * 4]);
  float s = v.x + v.y + v.z + v.w;
  float q = v.x * v.x + v.y * v.y + v.z * v.z + v.w * v.w;
  for (int off = 32; off; off >>= 1) { s += __shfl_down(s, off); q += __shfl_down(q, off); }
  __shared__ float ss[4], qq[4];
  int wid = tid >> 6, lane = tid & 63;
  if (lane == 0) { ss[wid] = s; qq[wid] = q; }
  __syncthreads();
  float St = ss[0] + ss[1] + ss[2] + ss[3];
  float Qt = qq[0] + qq[1] + qq[2] + qq[3];
  float mu  = St * (1.f / 1024.f);
  float var = Qt * (1.f / 1024.f) - mu * mu;
  float rstd = rsqrtf(var + 1e-6f);
  int c = tid * 4;
  unsigned short o[4];
  o[0] = f2b(g[c + 0] * (v.x - mu) * rstd + bta[c + 0]);
  o[1] = f2b(g[c + 1] * (v.y - mu) * rstd + bta[c + 1]);
  o[2] = f2b(g[c + 2] * (v.z - mu) * rstd + bta[c + 2]);
  o[3] = f2b(g[c + 3] * (v.w - mu) * rstd + bta[c + 3]);
  *reinterpret_cast<uint2*>(&xn[(size_t)row * 1024 + c]) = *reinterpret_cast<uint2*>(o);
}

// ---------------------------------------------------------------- flash attention
// grid (128 bh, 4 pairs); 512 thr = 8 waves x 16 q-rows. Block does q-tiles {y, 7-y}
// (balanced 18 k-tiles). Swapped QK^T: lane holds 16 scores of ONE q-row ->
// in-register softmax + 2 shuffles. Async reg-prefetch of next K/V tile.
__global__ __launch_bounds__(512, 4) void k_attn(const unsigned short* __restrict__ qkv,
                                                 unsigned short* __restrict__ o) {
  __shared__ unsigned short Ks[64][72];
  __shared__ unsigned short Vt[64][72];      // Vt[d][swz(k)], swz: k-blk ^= (d>>3)
  __shared__ unsigned short Pl[8][16][72];
  const int tid = threadIdx.x, lane = tid & 63, w = tid >> 6;
  const int bh = blockIdx.x, b = bh >> 4, h = bh & 15;
  const int lr = lane & 15, lg = lane >> 4, lg4 = lg * 4;
  const int krow = tid >> 3, c8 = (tid & 7) << 3;
  const int kb8 = krow >> 3, kl = krow & 7, vq = tid & 7;
  const float slope2 = exp2f(-0.5f * (float)(h + 1)) * 1.44269504f;
  const float sc2 = 0.125f * 1.44269504f;

  for (int ph = 0; ph < 2; ++ph) {
    const int qb = ph ? (7 - (int)blockIdx.y) : (int)blockIdx.y;
    const int q0 = qb * 128;
    const int qlo = q0 + w * 16;
    const int qa = qlo + lr;                 // this lane's q-row (for scores)

    bf16x8 qf[2];
    {
      const unsigned short* qp = &qkv[(size_t)(b * 1024 + qlo + lr) * 3072 + h * 64];
      qf[0] = *reinterpret_cast<const bf16x8*>(qp + lg * 8);
      qf[1] = *reinterpret_cast<const bf16x8*>(qp + 32 + lg * 8);
    }
    float mrun = -3.0e38f, lrun = 0.f;
    f32x4 accO[4];
    for (int dn = 0; dn < 4; dn++)
      for (int e = 0; e < 4; e++) accO[dn][e] = 0.f;

    const int nt = 2 * qb + 2;
    uint4 kr, vr;
    {
      const size_t base = (size_t)(b * 1024 + krow) * 3072 + h * 64;
      kr = *reinterpret_cast<const uint4*>(&qkv[base + 1024 + c8]);
      vr = *reinterpret_cast<const uint4*>(&qkv[base + 2048 + c8]);
    }
    for (int kt = 0; kt < nt; ++kt) {
      const int kb = kt << 6;
      __syncthreads();                        // prior tile's readers done
      *reinterpret_cast<uint4*>(&Ks[krow][c8]) = kr;
      {
        const unsigned short* vs = reinterpret_cast<const unsigned short*>(&vr);
        for (int j = 0; j < 8; j++)
          Vt[c8 + j][((kb8 ^ vq) << 3) | kl] = vs[j];
      }
      __syncthreads();                        // LDS ready
      if (kt + 1 < nt) {                      // prefetch next tile under compute
        const size_t base = (size_t)(b * 1024 + kb + 64 + krow) * 3072 + h * 64;
        kr = *reinterpret_cast<const uint4*>(&qkv[base + 1024 + c8]);
        vr = *reinterpret_cast<const uint4*>(&qkv[base + 2048 + c8]);
      }
      if (kb <= qlo + 15) {                   // wave-uniform skip of fully-masked tile
        f32x4 sf[4];
        for (int kn = 0; kn < 4; kn++) {
          f32x4 zz;
          for (int e = 0; e < 4; e++) zz[e] = 0.f;
          bf16x8 kf0 = *reinterpret_cast<const bf16x8*>(&Ks[kn * 16 + lr][lg * 8]);
          bf16x8 kf1 = *reinterpret_cast<const bf16x8*>(&Ks[kn * 16 + lr][32 + lg * 8]);
          zz = __builtin_amdgcn_mfma_f32_16x16x32_bf16(kf0, qf[0], zz, 0, 0, 0);
          zz = __builtin_amdgcn_mfma_f32_16x16x32_bf16(kf1, qf[1], zz, 0, 0, 0);
          sf[kn] = zz;                        // sf[kn][j]: k=kb+kn*16+lg4+j, q=qa
        }
        const bool needmask = (kb + 63 > qlo);
        float sc[4][4];
        float ml = -3.0e38f;
        for (int kn = 0; kn < 4; kn++) {
          float alib = slope2 * (float)(kb + kn * 16 + lg4);
          for (int j = 0; j < 4; j++) {
            float v = fmaf(sf[kn][j], sc2, alib + slope2 * (float)j);
            if (needmask && (kb + kn * 16 + lg4 + j > qa)) v = -3.0e38f;
            sc[kn][j] = v;
            ml = fmaxf(ml, v);
          }
        }
        ml = fmaxf(ml, __shfl_xor(ml, 16));
        ml = fmaxf(ml, __shfl_xor(ml, 32));
        float mnew = fmaxf(mrun, ml);
        float f = exp2f(mrun - mnew);
        float rs = 0.f;
        for (int kn = 0; kn < 4; kn++) {
          __bf16 pb[4];
          for (int j = 0; j < 4; j++) {
            float pv = exp2f(sc[kn][j] - mnew);
            rs += pv;
            pb[j] = (__bf16)pv;
          }
          *reinterpret_cast<uint2*>(&Pl[w][lr][kn * 16 + lg4]) =
              *reinterpret_cast<uint2*>(pb);
        }
        rs += __shfl_xor(rs, 16);
        rs += __shfl_xor(rs, 32);
        lrun = lrun * f + rs;
        mrun = mnew;
        float fj[4];
        for (int j = 0; j < 4; j++) fj[j] = __shfl(f, (lane & 48) | (lg4 + j));
        for (int dn = 0; dn < 4; dn++)
          for (int j = 0; j < 4; j++) accO[dn][j] *= fj[j];
        asm volatile("s_waitcnt lgkmcnt(0)" ::: "memory");   // own P writes drained
        for (int ks = 0; ks < 2; ks++) {
          bf16x8 pa = *reinterpret_cast<const bf16x8*>(&Pl[w][lr][ks * 32 + lg * 8]);
          for (int dn = 0; dn < 4; dn++) {
            int d = dn * 16 + lr;
            bf16x8 vb = *reinterpret_cast<const bf16x8*>(
                &Vt[d][(((ks * 4 + lg) ^ (d >> 3)) << 3)]);
            accO[dn] = __builtin_amdgcn_mfma_f32_16x16x32_bf16(pa, vb, accO[dn], 0, 0, 0);
          }
        }
      }
    }
    float linv[4];
    for (int j = 0; j < 4; j++)
      linv[j] = 1.f / __shfl(lrun, (lane & 48) | (lg4 + j));
    for (int dn = 0; dn < 4; dn++)
      for (int j = 0; j < 4; j++) {
        int row = qlo + lg4 + j;
        int d = dn * 16 + lr;
        o[(size_t)(b * 1024 + row) * 1024 + h * 64 + d] = f2b(accO[dn][j] * linv[j]);
      }
  }
}

// ---------------------------------------------------------------- decode GEMM (N=16) + transpose
__global__ __launch_bounds__(256) void k_dec(const unsigned short* __restrict__ xb,
                                             const unsigned short* __restrict__ dw,
                                             const float* __restrict__ db,
                                             float* __restrict__ out) {
  const int tid = threadIdx.x, lane = tid & 63, w = tid >> 6;
  const int lr = lane & 15, lg = lane >> 4;
  const int sb = blockIdx.x * 4 + w;
  const int r0 = sb * 16;
  f32x4 acc;
  for (int e = 0; e < 4; e++) acc[e] = 0.f;
  const unsigned short* arow = &xb[(size_t)(r0 + lr) * 1024];
  const unsigned short* brow = &dw[(size_t)lr * 1024];
  for (int k0 = 0; k0 < 1024; k0 += 32) {
    bf16x8 af = *reinterpret_cast<const bf16x8*>(arow + k0 + lg * 8);
    bf16x8 bf = *reinterpret_cast<const bf16x8*>(brow + k0 + lg * 8);
    acc = __builtin_amdgcn_mfma_f32_16x16x32_bf16(af, bf, acc, 0, 0, 0);
  }
  const int b = r0 >> 10;
  const int sl = (r0 & 1023) + lg * 4;
  float bias = db[lr];
  float4 res;
  res.x = acc[0] + bias; res.y = acc[1] + bias; res.z = acc[2] + bias; res.w = acc[3] + bias;
  *reinterpret_cast<float4*>(&out[(size_t)(b * 16 + lr) * 1024 + sl]) = res;
}

// ---------------------------------------------------------------- launcher
extern "C" void kernel_launch(void* const* d_in, const int* in_sizes, int n_in,
                              void* d_out, int out_size, void* d_ws, size_t ws_size,
                              hipStream_t stream) {
  (void)in_sizes; (void)n_in; (void)out_size;
  const float* z   = (const float*)d_in[0];
  const float* rt  = (const float*)d_in[1];
  const float* dnw = (const float*)d_in[2];
  const float* dnb = (const float*)d_in[3];
  const float* lng = (const float*)d_in[4];
  const float* lnb = (const float*)d_in[5];
  const float* wq  = (const float*)d_in[6];
  const float* bq  = (const float*)d_in[7];
  const float* wk  = (const float*)d_in[8];
  const float* bk  = (const float*)d_in[9];
  const float* wv  = (const float*)d_in[10];
  const float* bv  = (const float*)d_in[11];
  const float* wo  = (const float*)d_in[12];
  const float* bo  = (const float*)d_in[13];
  const float* dcw = (const float*)d_in[14];
  const float* dcb = (const float*)d_in[15];
  float* out = (float*)d_out;

  char* p = (char*)d_ws;
  float* x            = (float*)p;          p += (size_t)M * FDEC * 4;
  unsigned short* xin = (unsigned short*)p; p += (size_t)M * KP * 2;
  unsigned short* wdn = (unsigned short*)p; p += (size_t)FDEC * KP * 2;
  unsigned short* xn  = (unsigned short*)p; p += (size_t)M * FDEC * 2;
  unsigned short* w3  = (unsigned short*)p; p += (size_t)3 * FDEC * FDEC * 2;
  float* b3           = (float*)p;          p += (size_t)3 * FDEC * 4;
  unsigned short* qkv = (unsigned short*)p; p += (size_t)M * 3 * FDEC * 2;
  unsigned short* ob  = (unsigned short*)p; p += (size_t)M * FDEC * 2;
  unsigned short* wob = (unsigned short*)p; p += (size_t)FDEC * FDEC * 2;
  unsigned short* dwb = (unsigned short*)p; p += (size_t)FD * FDEC * 2;
  if ((size_t)(p - (char*)d_ws) > ws_size) return;

  k_prep_xin<<<(M * KP) / 256, 256, 0, stream>>>(z, rt, xin);
  k_cvt_pad<<<(FDEC * KP) / 256, 256, 0, stream>>>(dnw, wdn, FDEC, INK, KP);
  k_cvt_pad<<<(FDEC * FDEC) / 256, 256, 0, stream>>>(wq, w3, FDEC, FDEC, FDEC);
  k_cvt_pad<<<(FDEC * FDEC) / 256, 256, 0, stream>>>(wk, w3 + FDEC * FDEC, FDEC, FDEC, FDEC);
  k_cvt_pad<<<(FDEC * FDEC) / 256, 256, 0, stream>>>(wv, w3 + 2 * FDEC * FDEC, FDEC, FDEC, FDEC);
  k_cvt_pad<<<(FDEC * FDEC) / 256, 256, 0, stream>>>(wo, wob, FDEC, FDEC, FDEC);
  k_cvt_pad<<<(FD * FDEC) / 256, 256, 0, stream>>>(dcw, dwb, FD, FDEC, FDEC);
  k_b3<<<12, 256, 0, stream>>>(bq, bk, bv, b3);

  // grids: 1D, bid&7 = XCD, per-XCD chunk = 4 m-tiles x all n-tiles
  k_gemm<0><<<(M / 256) * (FDEC / 128), 512, 0, stream>>>(xin, KP, wdn, KP, KP, FDEC, dnb, x, nullptr);
  k_ln<<<M, 256, 0, stream>>>(x, lng, lnb, xn);
  k_gemm<1><<<(M / 256) * (3 * FDEC / 128), 512, 0, stream>>>(xn, FDEC, w3, FDEC, FDEC, 3 * FDEC, b3, nullptr, qkv);
  k_attn<<<dim3(Bn * H, 4), 512, 0, stream>>>(qkv, ob);
  k_gemm<2><<<(M / 256) * (FDEC / 128), 512, 0, stream>>>(ob, FDEC, wob, FDEC, FDEC, FDEC, bo, x, xn);
  k_dec<<<M / 64, 256, 0, stream>>>(xn, dwb, dcb, out);
}